// Round 1
// baseline (255.555 us; speedup 1.0000x reference)
//
#include <hip/hip_runtime.h>

// Problem constants (from setup_inputs): N=100000, E=3200000, H=256, G=128.
// All shapes are taken from in_sizes at launch; LDS arrays assume H<=256, G<=128.

#define GMAX 128
#define HMAX 256

// ---- K1: agg[dst] += x[src] over all edges (edge_index = [2,E]: src row, dst row)
__global__ __launch_bounds__(256) void edge_scatter(
    const int* __restrict__ ei, const float* __restrict__ x,
    float* __restrict__ agg, int E) {
  int t = blockIdx.x * blockDim.x + threadIdx.x;
  int n4 = E >> 2;
  const int4* src4 = (const int4*)ei;
  const int4* dst4 = (const int4*)(ei + E);
  if (t < n4) {
    int4 s = src4[t];
    int4 d = dst4[t];
    float xs0 = x[s.x], xs1 = x[s.y], xs2 = x[s.z], xs3 = x[s.w];
    atomicAdd(&agg[d.x], xs0);
    atomicAdd(&agg[d.y], xs1);
    atomicAdd(&agg[d.z], xs2);
    atomicAdd(&agg[d.w], xs3);
  }
  // tail (E not divisible by 4)
  int tail = E & 3;
  if (t < tail) {
    int e = (n4 << 2) + t;
    atomicAdd(&agg[ei[E + e]], x[ei[e]]);
  }
}

// ---- K2: per-node f(agg[i]) = sum_k relu(agg[i]*Wl[k]+bl[k])*Wout[k],
//          accumulated per graph via block-local LDS then global atomics.
__global__ __launch_bounds__(256) void node_kernel(
    const float* __restrict__ agg, const int* __restrict__ batch,
    const float* __restrict__ Wl, const float* __restrict__ bl,
    const float* __restrict__ Wout,
    float* __restrict__ gsum, float* __restrict__ gcnt, int N, int H) {
  __shared__ float sWl[HMAX], sbl[HMAX], sWo[HMAX];
  __shared__ float ls[GMAX], lc[GMAX];
  int tid = threadIdx.x;
  if (tid < H) { sWl[tid] = Wl[tid]; sbl[tid] = bl[tid]; sWo[tid] = Wout[tid]; }
  if (tid < GMAX) { ls[tid] = 0.f; lc[tid] = 0.f; }
  __syncthreads();

  int i = blockIdx.x * blockDim.x + tid;
  if (i < N) {
    float a = agg[i];
    float f = 0.f;
#pragma unroll 8
    for (int k = 0; k < H; ++k) {
      float h = fmaf(a, sWl[k], sbl[k]);
      f = fmaf(fmaxf(h, 0.f), sWo[k], f);
    }
    int g = batch[i];
    atomicAdd(&ls[g], f);
    atomicAdd(&lc[g], 1.f);
  }
  __syncthreads();
  if (tid < GMAX && lc[tid] > 0.f) {
    atomicAdd(&gsum[tid], ls[tid]);
    atomicAdd(&gcnt[tid], lc[tid]);
  }
}

// ---- K3: out[g] = relu(gsum[g]/max(gcnt[g],1) + b_out)
__global__ void final_kernel(const float* __restrict__ gsum,
                             const float* __restrict__ gcnt,
                             const float* __restrict__ b_out,
                             float* __restrict__ out, int G) {
  int g = blockIdx.x * blockDim.x + threadIdx.x;
  if (g < G) {
    float c = fmaxf(gcnt[g], 1.f);
    out[g] = fmaxf(gsum[g] / c + b_out[0], 0.f);
  }
}

extern "C" void kernel_launch(void* const* d_in, const int* in_sizes, int n_in,
                              void* d_out, int out_size, void* d_ws, size_t ws_size,
                              hipStream_t stream) {
  const float* x    = (const float*)d_in[0];
  const int*   ei   = (const int*)d_in[1];
  const int*   batch= (const int*)d_in[2];
  const float* Wl   = (const float*)d_in[3];
  const float* bl   = (const float*)d_in[4];
  const float* Wo   = (const float*)d_in[5];
  const float* bo   = (const float*)d_in[6];
  float* out = (float*)d_out;

  int N = in_sizes[0];          // 100000
  int E = in_sizes[1] / 2;      // 3200000
  int H = in_sizes[3];          // 256
  int G = out_size;             // 128

  // workspace layout: agg[N] | gsum[G] | gcnt[G]
  float* agg  = (float*)d_ws;
  float* gsum = agg + N;
  float* gcnt = gsum + G;

  // zero agg + gsum + gcnt (ws is re-poisoned to 0xAA before every call)
  hipMemsetAsync(d_ws, 0, (size_t)(N + 2 * G) * sizeof(float), stream);

  int n4 = (E + 3) / 4;
  int eb = (n4 + 255) / 256;
  edge_scatter<<<eb, 256, 0, stream>>>(ei, x, agg, E);

  int nb = (N + 255) / 256;
  node_kernel<<<nb, 256, 0, stream>>>(agg, batch, Wl, bl, Wo, gsum, gcnt, N, H);

  final_kernel<<<1, 128, 0, stream>>>(gsum, gcnt, bo, out, G);
}

// Round 2
// 248.054 us; speedup vs baseline: 1.0302x; 1.0302x over previous
//
#include <hip/hip_runtime.h>

// N=100000, E=3200000, H=256, G=128. LDS arrays assume H<=256, G<=128.
#define GMAX 128
#define HMAX 256
#define NXCD 8

// Physical XCD id of the executing wave (gfx940+/gfx950: hwreg 20).
// [measured: learn_hip m09 — returns 0..7 on MI355X]
__device__ __forceinline__ int get_xcc_id() {
  int x;
  asm volatile("s_getreg_b32 %0, hwreg(HW_REG_XCC_ID, 0, 4)" : "=s"(x));
  return x & (NXCD - 1);
}

// ---- K1: agg_r[xcd][dst] += x[src]. Workgroup-scope relaxed atomics execute
// in the local TCC (no sc1 write-through) — atomic across all CUs of this XCD,
// which are exactly the writers of this replica. Correct for ANY workgroup->XCD
// assignment; replicas are reduced in K2 after the dispatch-boundary writeback.
__global__ __launch_bounds__(256) void edge_scatter(
    const int* __restrict__ ei, const float* __restrict__ x,
    float* __restrict__ agg_r, int E, int N) {
  float* rep = agg_r + (size_t)get_xcc_id() * N;
  int t = blockIdx.x * blockDim.x + threadIdx.x;
  int n4 = E >> 2;
  const int4* src4 = (const int4*)ei;
  const int4* dst4 = (const int4*)(ei + E);
  if (t < n4) {
    int4 s = src4[t];
    int4 d = dst4[t];
    float x0 = x[s.x], x1 = x[s.y], x2 = x[s.z], x3 = x[s.w];
    __hip_atomic_fetch_add(&rep[d.x], x0, __ATOMIC_RELAXED, __HIP_MEMORY_SCOPE_WORKGROUP);
    __hip_atomic_fetch_add(&rep[d.y], x1, __ATOMIC_RELAXED, __HIP_MEMORY_SCOPE_WORKGROUP);
    __hip_atomic_fetch_add(&rep[d.z], x2, __ATOMIC_RELAXED, __HIP_MEMORY_SCOPE_WORKGROUP);
    __hip_atomic_fetch_add(&rep[d.w], x3, __ATOMIC_RELAXED, __HIP_MEMORY_SCOPE_WORKGROUP);
  }
  int tail = E & 3;
  if (t < tail) {
    int e = (n4 << 2) + t;
    __hip_atomic_fetch_add(&rep[ei[E + e]], x[ei[e]],
                           __ATOMIC_RELAXED, __HIP_MEMORY_SCOPE_WORKGROUP);
  }
}

// ---- K2: a[i] = sum over 8 replicas; f(a) = sum_k relu(a*Wl[k]+bl[k])*Wout[k];
//          per-graph accumulate via block LDS then one global atomic per graph.
__global__ __launch_bounds__(256) void node_kernel(
    const float* __restrict__ agg_r, const int* __restrict__ batch,
    const float* __restrict__ Wl, const float* __restrict__ bl,
    const float* __restrict__ Wout,
    float* __restrict__ gsum, float* __restrict__ gcnt, int N, int H) {
  __shared__ float sWl[HMAX], sbl[HMAX], sWo[HMAX];
  __shared__ float ls[GMAX], lc[GMAX];
  int tid = threadIdx.x;
  if (tid < H) { sWl[tid] = Wl[tid]; sbl[tid] = bl[tid]; sWo[tid] = Wout[tid]; }
  if (tid < GMAX) { ls[tid] = 0.f; lc[tid] = 0.f; }
  __syncthreads();

  int i = blockIdx.x * blockDim.x + tid;
  if (i < N) {
    float a = 0.f;
#pragma unroll
    for (int r = 0; r < NXCD; ++r) a += agg_r[(size_t)r * N + i];
    float f = 0.f;
#pragma unroll 8
    for (int k = 0; k < H; ++k) {
      float h = fmaf(a, sWl[k], sbl[k]);
      f = fmaf(fmaxf(h, 0.f), sWo[k], f);
    }
    int g = batch[i];
    atomicAdd(&ls[g], f);
    atomicAdd(&lc[g], 1.f);
  }
  __syncthreads();
  if (tid < GMAX && lc[tid] > 0.f) {
    atomicAdd(&gsum[tid], ls[tid]);
    atomicAdd(&gcnt[tid], lc[tid]);
  }
}

// ---- K3: out[g] = relu(gsum[g]/max(gcnt[g],1) + b_out)
__global__ void final_kernel(const float* __restrict__ gsum,
                             const float* __restrict__ gcnt,
                             const float* __restrict__ b_out,
                             float* __restrict__ out, int G) {
  int g = blockIdx.x * blockDim.x + threadIdx.x;
  if (g < G) {
    float c = fmaxf(gcnt[g], 1.f);
    out[g] = fmaxf(gsum[g] / c + b_out[0], 0.f);
  }
}

extern "C" void kernel_launch(void* const* d_in, const int* in_sizes, int n_in,
                              void* d_out, int out_size, void* d_ws, size_t ws_size,
                              hipStream_t stream) {
  const float* x     = (const float*)d_in[0];
  const int*   ei    = (const int*)d_in[1];
  const int*   batch = (const int*)d_in[2];
  const float* Wl    = (const float*)d_in[3];
  const float* bl    = (const float*)d_in[4];
  const float* Wo    = (const float*)d_in[5];
  const float* bo    = (const float*)d_in[6];
  float* out = (float*)d_out;

  int N = in_sizes[0];          // 100000
  int E = in_sizes[1] / 2;      // 3200000
  int H = in_sizes[3];          // 256
  int G = out_size;             // 128

  // workspace: agg_r[8][N] | gsum[G] | gcnt[G]
  float* agg_r = (float*)d_ws;
  float* gsum  = agg_r + (size_t)NXCD * N;
  float* gcnt  = gsum + G;

  hipMemsetAsync(d_ws, 0, ((size_t)NXCD * N + 2 * G) * sizeof(float), stream);

  int n4 = (E + 3) / 4;
  int eb = (n4 + 255) / 256;
  edge_scatter<<<eb, 256, 0, stream>>>(ei, x, agg_r, E, N);

  int nb = (N + 255) / 256;
  node_kernel<<<nb, 256, 0, stream>>>(agg_r, batch, Wl, bl, Wo, gsum, gcnt, N, H);

  final_kernel<<<1, 128, 0, stream>>>(gsum, gcnt, bo, out, G);
}

// Round 3
// 156.629 us; speedup vs baseline: 1.6316x; 1.5837x over previous
//
#include <hip/hip_runtime.h>

// N=100000, E=3200000, H=256, G=128.
// Strategy: global fp32 scatter-atomics measured at ~20 G ops/s on gfx950
// (3.2M atomics = 160 us, WRITE_SIZE = 32 B/atomic). So we bin edges by
// dst-range into contiguous buckets (exact offsets via histogram+prefix),
// then reduce each bucket in LDS with ds_add_f32 — ~100k global atomics total.

#define GMAX  128      // max graphs
#define HMAX  256      // max hidden dim
#define BS    256      // nodes per bucket (dst >> 8)
#define NBMAX 512      // max buckets (N <= 131072)
#define S_GRID 128     // blocks for S1/S2

// ---------------- main path ----------------

// S1: global bucket histogram. LDS hist -> one global int atomic per (block,bucket).
__global__ __launch_bounds__(256) void s1_hist(const int* __restrict__ ei,
                                               unsigned* __restrict__ bucketCnt,
                                               int E, int NB) {
  __shared__ unsigned h[NBMAX];
  for (int b = threadIdx.x; b < NB; b += 256) h[b] = 0u;
  __syncthreads();
  int Q = E >> 2;
  const int4* d4 = (const int4*)(ei + E);
  int gid = blockIdx.x * 256 + threadIdx.x, stride = S_GRID * 256;
  for (int q = gid; q < Q; q += stride) {
    int4 d = d4[q];
    atomicAdd(&h[d.x >> 8], 1u);
    atomicAdd(&h[d.y >> 8], 1u);
    atomicAdd(&h[d.z >> 8], 1u);
    atomicAdd(&h[d.w >> 8], 1u);
  }
  for (int e = (Q << 2) + gid; e < E; e += stride)   // tail (E % 4)
    atomicAdd(&h[ei[E + e] >> 8], 1u);
  __syncthreads();
  for (int b = threadIdx.x; b < NB; b += 256)
    if (h[b]) atomicAdd(&bucketCnt[b], h[b]);
}

// Prefix: exclusive scan of 4-padded counts -> 16B-aligned bucket bases.
__global__ __launch_bounds__(NBMAX) void s_prefix(const unsigned* __restrict__ bucketCnt,
                                                  unsigned* __restrict__ base,
                                                  unsigned* __restrict__ cursor, int NB) {
  __shared__ unsigned s[NBMAX];
  int t = threadIdx.x;
  unsigned c = (t < NB) ? ((bucketCnt[t] + 3u) & ~3u) : 0u;
  s[t] = c;
  __syncthreads();
  for (int off = 1; off < NBMAX; off <<= 1) {
    unsigned v = (t >= off) ? s[t - off] : 0u;
    __syncthreads();
    s[t] += v;
    __syncthreads();
  }
  if (t < NB) {
    unsigned excl = s[t] - c;
    base[t] = excl;
    cursor[t] = excl;
  }
}

// S2: scatter edges into buckets. Per-block LDS counts -> one global cursor
// reservation atomic per (block,bucket); pairs written as (src<<8)|dst_local.
__global__ __launch_bounds__(256) void s2_scatter(const int* __restrict__ ei,
                                                  unsigned* __restrict__ cursor,
                                                  unsigned* __restrict__ pairs,
                                                  int E, int NB) {
  __shared__ unsigned h[NBMAX];     // counts, then local base
  __shared__ unsigned rcur[NBMAX];  // local running rank
  for (int b = threadIdx.x; b < NB; b += 256) { h[b] = 0u; rcur[b] = 0u; }
  __syncthreads();
  int Q = E >> 2;
  const int4* s4 = (const int4*)ei;
  const int4* d4 = (const int4*)(ei + E);
  int gid = blockIdx.x * 256 + threadIdx.x, stride = S_GRID * 256;
  // pass A: count
  for (int q = gid; q < Q; q += stride) {
    int4 d = d4[q];
    atomicAdd(&h[d.x >> 8], 1u);
    atomicAdd(&h[d.y >> 8], 1u);
    atomicAdd(&h[d.z >> 8], 1u);
    atomicAdd(&h[d.w >> 8], 1u);
  }
  for (int e = (Q << 2) + gid; e < E; e += stride)
    atomicAdd(&h[ei[E + e] >> 8], 1u);
  __syncthreads();
  // reserve
  for (int b = threadIdx.x; b < NB; b += 256) {
    unsigned c = h[b];
    h[b] = c ? atomicAdd(&cursor[b], c) : 0u;
  }
  __syncthreads();
  // pass B: scatter
  for (int q = gid; q < Q; q += stride) {
    int4 s = s4[q];
    int4 d = d4[q];
    { int b = d.x >> 8; unsigned r = atomicAdd(&rcur[b], 1u);
      pairs[h[b] + r] = ((unsigned)s.x << 8) | (unsigned)(d.x & 255); }
    { int b = d.y >> 8; unsigned r = atomicAdd(&rcur[b], 1u);
      pairs[h[b] + r] = ((unsigned)s.y << 8) | (unsigned)(d.y & 255); }
    { int b = d.z >> 8; unsigned r = atomicAdd(&rcur[b], 1u);
      pairs[h[b] + r] = ((unsigned)s.z << 8) | (unsigned)(d.z & 255); }
    { int b = d.w >> 8; unsigned r = atomicAdd(&rcur[b], 1u);
      pairs[h[b] + r] = ((unsigned)s.w << 8) | (unsigned)(d.w & 255); }
  }
  for (int e = (Q << 2) + gid; e < E; e += stride) {
    int d = ei[E + e], s = ei[e];
    int b = d >> 8; unsigned r = atomicAdd(&rcur[b], 1u);
    pairs[h[b] + r] = ((unsigned)s << 8) | (unsigned)(d & 255);
  }
}

// S3 (fused): bucket reduce in LDS, then per-node f(a) and per-graph pooling.
// f(a) = sum_k relu(a*Wl[k]+bl[k])*Wo[k]  (pool-mean and out-dot are linear).
__global__ __launch_bounds__(256) void s3_reduce(
    const unsigned* __restrict__ pairs, const unsigned* __restrict__ base,
    const unsigned* __restrict__ bucketCnt,
    const float* __restrict__ x, const int* __restrict__ batch,
    const float* __restrict__ Wl, const float* __restrict__ bl,
    const float* __restrict__ Wo,
    float* __restrict__ gsum, float* __restrict__ gcnt, int N, int H) {
  __shared__ float acc[BS];
  __shared__ float sWl[HMAX], sbl[HMAX], sWo[HMAX];
  __shared__ float ls[GMAX], lc[GMAX];
  int tid = threadIdx.x, b = blockIdx.x;
  acc[tid] = 0.f;
  if (tid < H) { sWl[tid] = Wl[tid]; sbl[tid] = bl[tid]; sWo[tid] = Wo[tid]; }
  if (tid < GMAX) { ls[tid] = 0.f; lc[tid] = 0.f; }
  __syncthreads();

  unsigned lo = base[b], cnt = bucketCnt[b];
  unsigned q4 = cnt >> 2;
  const uint4* p4 = (const uint4*)(pairs + lo);   // lo is 4-aligned by prefix padding
  for (unsigned i = tid; i < q4; i += 256) {
    uint4 p = p4[i];
    atomicAdd(&acc[p.x & 255u], x[p.x >> 8]);
    atomicAdd(&acc[p.y & 255u], x[p.y >> 8]);
    atomicAdd(&acc[p.z & 255u], x[p.z >> 8]);
    atomicAdd(&acc[p.w & 255u], x[p.w >> 8]);
  }
  if (tid < (int)(cnt & 3u)) {
    unsigned p = pairs[lo + (q4 << 2) + tid];
    atomicAdd(&acc[p & 255u], x[p >> 8]);
  }
  __syncthreads();

  int node = b * BS + tid;
  if (node < N) {
    float a = acc[tid], f = 0.f;
#pragma unroll 8
    for (int k = 0; k < H; ++k) {
      float hh = fmaf(a, sWl[k], sbl[k]);
      f = fmaf(fmaxf(hh, 0.f), sWo[k], f);
    }
    int g = batch[node];
    atomicAdd(&ls[g], f);
    atomicAdd(&lc[g], 1.f);
  }
  __syncthreads();
  if (tid < GMAX && lc[tid] != 0.f) {
    atomicAdd(&gsum[tid], ls[tid]);
    atomicAdd(&gcnt[tid], lc[tid]);
  }
}

// final: out[g] = relu(gsum/max(gcnt,1) + b_out)
__global__ void final_kernel(const float* __restrict__ gsum,
                             const float* __restrict__ gcnt,
                             const float* __restrict__ b_out,
                             float* __restrict__ out, int G) {
  int g = blockIdx.x * blockDim.x + threadIdx.x;
  if (g < G) {
    float c = fmaxf(gcnt[g], 1.f);
    out[g] = fmaxf(gsum[g] / c + b_out[0], 0.f);
  }
}

// ---------------- fallback path (small ws or oversized N) ----------------

__global__ __launch_bounds__(256) void fb_scatter(const int* __restrict__ ei,
                                                  const float* __restrict__ x,
                                                  float* __restrict__ agg, int E) {
  int t = blockIdx.x * blockDim.x + threadIdx.x;
  if (t < E) atomicAdd(&agg[ei[E + t]], x[ei[t]]);
}

__global__ __launch_bounds__(256) void fb_node(const float* __restrict__ agg,
                                               const int* __restrict__ batch,
                                               const float* __restrict__ Wl,
                                               const float* __restrict__ bl,
                                               const float* __restrict__ Wo,
                                               float* __restrict__ gsum,
                                               float* __restrict__ gcnt, int N, int H) {
  __shared__ float sWl[HMAX], sbl[HMAX], sWo[HMAX];
  __shared__ float ls[GMAX], lc[GMAX];
  int tid = threadIdx.x;
  if (tid < H) { sWl[tid] = Wl[tid]; sbl[tid] = bl[tid]; sWo[tid] = Wo[tid]; }
  if (tid < GMAX) { ls[tid] = 0.f; lc[tid] = 0.f; }
  __syncthreads();
  int i = blockIdx.x * blockDim.x + tid;
  if (i < N) {
    float a = agg[i], f = 0.f;
    for (int k = 0; k < H; ++k) {
      float hh = fmaf(a, sWl[k], sbl[k]);
      f = fmaf(fmaxf(hh, 0.f), sWo[k], f);
    }
    int g = batch[i];
    atomicAdd(&ls[g], f);
    atomicAdd(&lc[g], 1.f);
  }
  __syncthreads();
  if (tid < GMAX && lc[tid] != 0.f) {
    atomicAdd(&gsum[tid], ls[tid]);
    atomicAdd(&gcnt[tid], lc[tid]);
  }
}

// ---------------- launch ----------------

extern "C" void kernel_launch(void* const* d_in, const int* in_sizes, int n_in,
                              void* d_out, int out_size, void* d_ws, size_t ws_size,
                              hipStream_t stream) {
  const float* x     = (const float*)d_in[0];
  const int*   ei    = (const int*)d_in[1];
  const int*   batch = (const int*)d_in[2];
  const float* Wl    = (const float*)d_in[3];
  const float* bl    = (const float*)d_in[4];
  const float* Wo    = (const float*)d_in[5];
  const float* bo    = (const float*)d_in[6];
  float* out = (float*)d_out;

  int N = in_sizes[0];        // 100000
  int E = in_sizes[1] / 2;    // 3200000
  int H = in_sizes[3];        // 256
  int G = out_size;           // 128

  int NB = (N + BS - 1) / BS; // 391

  // ws word layout:
  //   [0,NBMAX)            bucketCnt
  //   [NBMAX,2*NBMAX)      base
  //   [2*NBMAX,3*NBMAX)    cursor
  //   [3*NBMAX,+GMAX)      gsum   (float)
  //   [.. +GMAX)           gcnt   (float)
  //   [HDR, HDR+E+3*NB)    pairs  (u32) — HDR*4 is 16B-aligned
  const int HDR = 3 * NBMAX + 2 * GMAX; // 1792 words
  size_t need = ((size_t)HDR + (size_t)E + 3u * (size_t)NB) * 4u;

  unsigned* w = (unsigned*)d_ws;
  if (NB <= NBMAX && ws_size >= need && H <= HMAX && G <= GMAX) {
    unsigned* bucketCnt = w;
    unsigned* base      = w + NBMAX;
    unsigned* cursor    = w + 2 * NBMAX;
    float*    gsum      = (float*)(w + 3 * NBMAX);
    float*    gcnt      = gsum + GMAX;
    unsigned* pairs     = w + HDR;

    hipMemsetAsync(d_ws, 0, (size_t)HDR * 4u, stream);
    s1_hist<<<S_GRID, 256, 0, stream>>>(ei, bucketCnt, E, NB);
    s_prefix<<<1, NBMAX, 0, stream>>>(bucketCnt, base, cursor, NB);
    s2_scatter<<<S_GRID, 256, 0, stream>>>(ei, cursor, pairs, E, NB);
    s3_reduce<<<NB, 256, 0, stream>>>(pairs, base, bucketCnt, x, batch,
                                      Wl, bl, Wo, gsum, gcnt, N, H);
    final_kernel<<<1, 128, 0, stream>>>(gsum, gcnt, bo, out, G);
  } else {
    // fallback: direct atomics (slow but ws-light)
    float* agg  = (float*)d_ws;
    float* gsum = agg + N;
    float* gcnt = gsum + GMAX;
    hipMemsetAsync(d_ws, 0, ((size_t)N + 2 * GMAX) * 4u, stream);
    fb_scatter<<<(E + 255) / 256, 256, 0, stream>>>(ei, x, agg, E);
    fb_node<<<(N + 255) / 256, 256, 0, stream>>>(agg, batch, Wl, bl, Wo,
                                                 gsum, gcnt, N, H);
    final_kernel<<<1, 128, 0, stream>>>(gsum, gcnt, bo, out, G);
  }
}

// Round 4
// 147.546 us; speedup vs baseline: 1.7320x; 1.0616x over previous
//
#include <hip/hip_runtime.h>

// N=100000, E=3200000, H=256, G=128.
// Pipeline: bin edges by dst>>8 into exact contiguous buckets (per-block dense
// histograms + 2D prefix scan -> zero global atomics in the binning), then
// reduce each bucket in LDS (ds_add_f32) fused with the collapsed per-node
// MLP  f(a)=sum_k relu(a*Wl[k]+bl[k])*Wo[k]  and per-graph mean pooling.
// Round-3 lesson: grid=128 -> 4.5% occupancy, latency-bound. Now grid=512.

#define GMAX  128      // max graphs
#define HMAX  256      // max hidden dim
#define BS    256      // nodes per bucket (dst >> 8)
#define NBMAX 512      // max buckets (N <= 131072)
#define SG    512      // blocks for s1/s2 (also width of the 2D prefix)

// ---------------- main path ----------------

// S1: per-block dense histogram of dst buckets. No global atomics:
// cnt[bucket][block] written densely.
__global__ __launch_bounds__(256) void s1_count(const int* __restrict__ ei,
                                                unsigned* __restrict__ cnt,
                                                int E, int NB, int QpB) {
  __shared__ unsigned h[NBMAX];
  int tid = threadIdx.x;
  for (int b = tid; b < NB; b += 256) h[b] = 0u;
  __syncthreads();
  int Q = E >> 2;
  int q0 = blockIdx.x * QpB;
  int q1 = min(q0 + QpB, Q);
  const int4* d4 = (const int4*)(ei + E);
  for (int q = q0 + tid; q < q1; q += 256) {
    int4 d = d4[q];
    atomicAdd(&h[d.x >> 8], 1u);
    atomicAdd(&h[d.y >> 8], 1u);
    atomicAdd(&h[d.z >> 8], 1u);
    atomicAdd(&h[d.w >> 8], 1u);
  }
  if (blockIdx.x == 0)   // tail edges (E % 4) counted by block 0
    for (int e = (Q << 2) + tid; e < E; e += 256)
      atomicAdd(&h[ei[E + e] >> 8], 1u);
  __syncthreads();
  for (int b = tid; b < NB; b += 256) cnt[(size_t)b * SG + blockIdx.x] = h[b];
}

// scanA: per bucket, exclusive scan of the SG per-block counts -> off, total.
__global__ __launch_bounds__(SG) void s_scanA(const unsigned* __restrict__ cnt,
                                              unsigned* __restrict__ off,
                                              unsigned* __restrict__ tot) {
  __shared__ unsigned s[SG];
  int b = blockIdx.x, t = threadIdx.x;
  unsigned c = cnt[(size_t)b * SG + t];
  s[t] = c;
  __syncthreads();
  for (int o = 1; o < SG; o <<= 1) {
    unsigned v = (t >= o) ? s[t - o] : 0u;
    __syncthreads();
    s[t] += v;
    __syncthreads();
  }
  off[(size_t)b * SG + t] = s[t] - c;
  if (t == SG - 1) tot[b] = s[t];
}

// scanB: exclusive scan of 4-padded bucket totals -> 16B-aligned bucket bases.
__global__ __launch_bounds__(NBMAX) void s_scanB(const unsigned* __restrict__ tot,
                                                 unsigned* __restrict__ base, int NB) {
  __shared__ unsigned s[NBMAX];
  int t = threadIdx.x;
  unsigned c = (t < NB) ? ((tot[t] + 3u) & ~3u) : 0u;
  s[t] = c;
  __syncthreads();
  for (int o = 1; o < NBMAX; o <<= 1) {
    unsigned v = (t >= o) ? s[t - o] : 0u;
    __syncthreads();
    s[t] += v;
    __syncthreads();
  }
  if (t < NB) base[t] = s[t] - c;
}

// S2: scatter edges into buckets at precomputed bases; only LDS rank atomics.
// pairs[slot] = (src<<8) | (dst & 255).
__global__ __launch_bounds__(256) void s2_scatter(const int* __restrict__ ei,
                                                  const unsigned* __restrict__ off,
                                                  const unsigned* __restrict__ base,
                                                  unsigned* __restrict__ pairs,
                                                  int E, int NB, int QpB) {
  __shared__ unsigned hb[NBMAX];    // my block's write base per bucket
  __shared__ unsigned rcur[NBMAX];  // local running rank
  int tid = threadIdx.x;
  for (int b = tid; b < NB; b += 256) {
    hb[b] = base[b] + off[(size_t)b * SG + blockIdx.x];
    rcur[b] = 0u;
  }
  __syncthreads();
  int Q = E >> 2;
  int q0 = blockIdx.x * QpB;
  int q1 = min(q0 + QpB, Q);
  const int4* s4 = (const int4*)ei;
  const int4* d4 = (const int4*)(ei + E);
  for (int q = q0 + tid; q < q1; q += 256) {
    int4 s = s4[q];
    int4 d = d4[q];
    { int b = d.x >> 8; unsigned r = atomicAdd(&rcur[b], 1u);
      pairs[hb[b] + r] = ((unsigned)s.x << 8) | (unsigned)(d.x & 255); }
    { int b = d.y >> 8; unsigned r = atomicAdd(&rcur[b], 1u);
      pairs[hb[b] + r] = ((unsigned)s.y << 8) | (unsigned)(d.y & 255); }
    { int b = d.z >> 8; unsigned r = atomicAdd(&rcur[b], 1u);
      pairs[hb[b] + r] = ((unsigned)s.z << 8) | (unsigned)(d.z & 255); }
    { int b = d.w >> 8; unsigned r = atomicAdd(&rcur[b], 1u);
      pairs[hb[b] + r] = ((unsigned)s.w << 8) | (unsigned)(d.w & 255); }
  }
  if (blockIdx.x == 0)   // tail edges, matching s1_count
    for (int e = (Q << 2) + tid; e < E; e += 256) {
      int d = ei[E + e], s = ei[e];
      int b = d >> 8; unsigned r = atomicAdd(&rcur[b], 1u);
      pairs[hb[b] + r] = ((unsigned)s << 8) | (unsigned)(d & 255);
    }
}

// S3 (fused): bucket reduce in LDS, then per-node f(a) and per-graph pooling.
__global__ __launch_bounds__(256) void s3_reduce(
    const unsigned* __restrict__ pairs, const unsigned* __restrict__ base,
    const unsigned* __restrict__ tot,
    const float* __restrict__ x, const int* __restrict__ batch,
    const float* __restrict__ Wl, const float* __restrict__ bl,
    const float* __restrict__ Wo,
    float* __restrict__ gsum, float* __restrict__ gcnt, int N, int H) {
  __shared__ float acc[BS];
  __shared__ float sWl[HMAX], sbl[HMAX], sWo[HMAX];
  __shared__ float ls[GMAX], lc[GMAX];
  int tid = threadIdx.x, b = blockIdx.x;
  acc[tid] = 0.f;
  if (tid < H) { sWl[tid] = Wl[tid]; sbl[tid] = bl[tid]; sWo[tid] = Wo[tid]; }
  if (tid < GMAX) { ls[tid] = 0.f; lc[tid] = 0.f; }
  __syncthreads();

  unsigned lo = base[b], cnt = tot[b];
  unsigned q4 = cnt >> 2;
  const uint4* p4 = (const uint4*)(pairs + lo);   // lo 4-aligned via padded scan
  for (unsigned i = tid; i < q4; i += 256) {
    uint4 p = p4[i];
    atomicAdd(&acc[p.x & 255u], x[p.x >> 8]);
    atomicAdd(&acc[p.y & 255u], x[p.y >> 8]);
    atomicAdd(&acc[p.z & 255u], x[p.z >> 8]);
    atomicAdd(&acc[p.w & 255u], x[p.w >> 8]);
  }
  if (tid < (int)(cnt & 3u)) {
    unsigned p = pairs[lo + (q4 << 2) + tid];
    atomicAdd(&acc[p & 255u], x[p >> 8]);
  }
  __syncthreads();

  int node = b * BS + tid;
  if (node < N) {
    float a = acc[tid], f = 0.f;
#pragma unroll 8
    for (int k = 0; k < H; ++k) {
      float hh = fmaf(a, sWl[k], sbl[k]);
      f = fmaf(fmaxf(hh, 0.f), sWo[k], f);
    }
    int g = batch[node];
    atomicAdd(&ls[g], f);
    atomicAdd(&lc[g], 1.f);
  }
  __syncthreads();
  if (tid < GMAX && lc[tid] != 0.f) {
    atomicAdd(&gsum[tid], ls[tid]);
    atomicAdd(&gcnt[tid], lc[tid]);
  }
}

__global__ void final_kernel(const float* __restrict__ gsum,
                             const float* __restrict__ gcnt,
                             const float* __restrict__ b_out,
                             float* __restrict__ out, int G) {
  int g = blockIdx.x * blockDim.x + threadIdx.x;
  if (g < G) {
    float c = fmaxf(gcnt[g], 1.f);
    out[g] = fmaxf(gsum[g] / c + b_out[0], 0.f);
  }
}

// ---------------- fallback path (small ws or oversized N) ----------------

__global__ __launch_bounds__(256) void fb_scatter(const int* __restrict__ ei,
                                                  const float* __restrict__ x,
                                                  float* __restrict__ agg, int E) {
  int t = blockIdx.x * blockDim.x + threadIdx.x;
  if (t < E) atomicAdd(&agg[ei[E + t]], x[ei[t]]);
}

__global__ __launch_bounds__(256) void fb_node(const float* __restrict__ agg,
                                               const int* __restrict__ batch,
                                               const float* __restrict__ Wl,
                                               const float* __restrict__ bl,
                                               const float* __restrict__ Wo,
                                               float* __restrict__ gsum,
                                               float* __restrict__ gcnt, int N, int H) {
  __shared__ float sWl[HMAX], sbl[HMAX], sWo[HMAX];
  __shared__ float ls[GMAX], lc[GMAX];
  int tid = threadIdx.x;
  if (tid < H) { sWl[tid] = Wl[tid]; sbl[tid] = bl[tid]; sWo[tid] = Wo[tid]; }
  if (tid < GMAX) { ls[tid] = 0.f; lc[tid] = 0.f; }
  __syncthreads();
  int i = blockIdx.x * blockDim.x + tid;
  if (i < N) {
    float a = agg[i], f = 0.f;
    for (int k = 0; k < H; ++k) {
      float hh = fmaf(a, sWl[k], sbl[k]);
      f = fmaf(fmaxf(hh, 0.f), sWo[k], f);
    }
    int g = batch[i];
    atomicAdd(&ls[g], f);
    atomicAdd(&lc[g], 1.f);
  }
  __syncthreads();
  if (tid < GMAX && lc[tid] != 0.f) {
    atomicAdd(&gsum[tid], ls[tid]);
    atomicAdd(&gcnt[tid], lc[tid]);
  }
}

// ---------------- launch ----------------

extern "C" void kernel_launch(void* const* d_in, const int* in_sizes, int n_in,
                              void* d_out, int out_size, void* d_ws, size_t ws_size,
                              hipStream_t stream) {
  const float* x     = (const float*)d_in[0];
  const int*   ei    = (const int*)d_in[1];
  const int*   batch = (const int*)d_in[2];
  const float* Wl    = (const float*)d_in[3];
  const float* bl    = (const float*)d_in[4];
  const float* Wo    = (const float*)d_in[5];
  const float* bo    = (const float*)d_in[6];
  float* out = (float*)d_out;

  int N = in_sizes[0];        // 100000
  int E = in_sizes[1] / 2;    // 3200000
  int H = in_sizes[3];        // 256
  int G = out_size;           // 128

  int NB = (N + BS - 1) / BS; // 391
  int Q  = E >> 2;
  int QpB = (Q + SG - 1) / SG;

  // ws word layout:
  //   cnt  [NBMAX*SG]       per-(bucket,block) counts
  //   off  [NBMAX*SG]       per-(bucket,block) exclusive offsets
  //   tot  [NBMAX]          bucket totals
  //   base [NBMAX]          4-padded exclusive bucket bases
  //   gsum [GMAX], gcnt [GMAX]
  //   pairs[E + 3*NB]
  const size_t W_CNT  = (size_t)NBMAX * SG;
  const size_t W_OFF  = W_CNT;
  const size_t HDRW   = W_CNT + W_OFF + 2 * NBMAX + 2 * GMAX;
  size_t need = (HDRW + (size_t)E + 3u * (size_t)NB) * 4u;

  unsigned* w = (unsigned*)d_ws;
  if (NB <= NBMAX && ws_size >= need && H <= HMAX && G <= GMAX) {
    unsigned* cnt   = w;
    unsigned* off   = cnt + W_CNT;
    unsigned* tot   = off + W_OFF;
    unsigned* base  = tot + NBMAX;
    float*    gsum  = (float*)(base + NBMAX);
    float*    gcnt  = gsum + GMAX;
    unsigned* pairs = (unsigned*)(gcnt + GMAX);

    hipMemsetAsync(gsum, 0, 2u * GMAX * sizeof(float), stream);
    s1_count<<<SG, 256, 0, stream>>>(ei, cnt, E, NB, QpB);
    s_scanA<<<NB, SG, 0, stream>>>(cnt, off, tot);
    s_scanB<<<1, NBMAX, 0, stream>>>(tot, base, NB);
    s2_scatter<<<SG, 256, 0, stream>>>(ei, off, base, pairs, E, NB, QpB);
    s3_reduce<<<NB, 256, 0, stream>>>(pairs, base, tot, x, batch,
                                      Wl, bl, Wo, gsum, gcnt, N, H);
    final_kernel<<<1, 128, 0, stream>>>(gsum, gcnt, bo, out, G);
  } else {
    float* agg  = (float*)d_ws;
    float* gsum = agg + N;
    float* gcnt = gsum + GMAX;
    hipMemsetAsync(d_ws, 0, ((size_t)N + 2 * GMAX) * 4u, stream);
    fb_scatter<<<(E + 255) / 256, 256, 0, stream>>>(ei, x, agg, E);
    fb_node<<<(N + 255) / 256, 256, 0, stream>>>(agg, batch, Wl, bl, Wo,
                                                 gsum, gcnt, N, H);
    final_kernel<<<1, 128, 0, stream>>>(gsum, gcnt, bo, out, G);
  }
}